// Round 1
// baseline (693.163 us; speedup 1.0000x reference)
//
#include <hip/hip_runtime.h>
#include <stdint.h>

#define DI __device__ __forceinline__

typedef __attribute__((ext_vector_type(8))) short bfx8;
typedef __attribute__((ext_vector_type(4))) short bfx4;
typedef __attribute__((ext_vector_type(4))) float f4;

DI unsigned short f2bf(float x){
  unsigned u = __float_as_uint(x);
  u = (u + 0x7FFFu + ((u >> 16) & 1u)) >> 16;
  return (unsigned short)u;
}
DI float bf2f(unsigned short h){ return __uint_as_float(((unsigned)h) << 16); }

DI f4 mfma32(bfx8 a, bfx8 b, f4 c){
  return __builtin_amdgcn_mfma_f32_16x16x32_bf16(a, b, c, 0, 0, 0);
}
#if __has_builtin(__builtin_amdgcn_mfma_f32_16x16x16bf16_1k)
DI f4 mfma16(bfx4 a, bfx4 b, f4 c){
  return __builtin_amdgcn_mfma_f32_16x16x16bf16_1k(a, b, c, 0, 0, 0);
}
#else
DI f4 mfma16(bfx4 a, bfx4 b, f4 c){
  f4 d = c;
  asm volatile("v_mfma_f32_16x16x16_bf16 %0, %1, %2, %0" : "+v"(d) : "v"(a), "v"(b));
  return d;
}
#endif

// ---------------- cast f32 -> bf16 (4-wide) ----------------
__global__ void k_cast(const float* __restrict__ src, unsigned short* __restrict__ dst, int n4){
  int i = blockIdx.x*256 + threadIdx.x;
  if (i < n4){
    const float4 v = ((const float4*)src)[i];
    bfx4 o;
    o[0] = (short)f2bf(v.x); o[1] = (short)f2bf(v.y);
    o[2] = (short)f2bf(v.z); o[3] = (short)f2bf(v.w);
    *(bfx4*)(dst + (size_t)i*4) = o;
  }
}

// relk_bf: [272][64] zero-padded rows; relvT_bf: [64][288] = rel_v^T zero-padded cols
__global__ void k_relprep(const float* __restrict__ rlk, const float* __restrict__ rlv,
                          unsigned short* __restrict__ relk_bf, unsigned short* __restrict__ relvT_bf){
  int i = blockIdx.x*256 + threadIdx.x;
  if (i < 272*64){
    int r = i >> 6, d = i & 63;
    relk_bf[i] = (r < 257) ? f2bf(rlk[r*64 + d]) : (unsigned short)0;
  }
  if (i < 64*288){
    int d = i / 288, r = i % 288;
    relvT_bf[i] = (r < 257) ? f2bf(rlv[(size_t)r*64 + d]) : (unsigned short)0;
  }
}

// ---------------- QK projection: D[sb'][n] = x @ w^T ; Q scaled by 1/8 ----------------
// rows sb' = b*1024+s (memory row = s*4+b). Q/K layout: [b][h][s][d]
__global__ __launch_bounds__(256) void k_qk(
    const unsigned short* __restrict__ xbf, const unsigned short* __restrict__ wq,
    const unsigned short* __restrict__ wk, unsigned short* __restrict__ Qb,
    unsigned short* __restrict__ Kb)
{
  const int w = threadIdx.x >> 6, lane = threadIdx.x & 63;
  const int p = lane & 15, g = lane >> 4;
  const int r0 = blockIdx.x*64 + w*16;
  const int b = r0 >> 10, s0 = r0 & 1023;
  const int n0 = blockIdx.y*64;
  const bool isQ = (n0 < 1024);
  const unsigned short* wsel = isQ ? wq : wk;
  const int nn0 = n0 & 1023;
  const f4 fz = {0.f,0.f,0.f,0.f};
  f4 acc[4] = {fz,fz,fz,fz};
  const unsigned short* arow = xbf + ((size_t)((s0 + p)*4 + b))*1024;
  for (int k0=0; k0<1024; k0+=32){
    bfx8 a = *(const bfx8*)(arow + k0 + 8*g);
#pragma unroll
    for (int f=0; f<4; ++f){
      bfx8 bb = *(const bfx8*)(wsel + (size_t)(nn0 + 16*f + p)*1024 + k0 + 8*g);
      acc[f] = mfma32(a, bb, acc[f]);
    }
  }
  unsigned short* dst = isQ ? Qb : Kb;
  const float scl = isQ ? 0.125f : 1.0f;
#pragma unroll
  for (int f=0; f<4; ++f){
    int col = nn0 + 16*f + p;
    int h = col >> 6, d = col & 63;
#pragma unroll
    for (int r=0; r<4; ++r){
      int srow = s0 + 4*g + r;
      dst[((size_t)(b*16 + h)*1024 + srow)*64 + d] = f2bf(acc[f][r] * scl);
    }
  }
}

// ---------------- V projection transposed: D'[n][sb'] = w_v @ x^T ; VT layout [b][h][d][s] ----------------
__global__ __launch_bounds__(256) void k_v(
    const unsigned short* __restrict__ xbf, const unsigned short* __restrict__ wv,
    unsigned short* __restrict__ VT)
{
  const int w = threadIdx.x >> 6, lane = threadIdx.x & 63;
  const int p = lane & 15, g = lane >> 4;
  const int n0 = blockIdx.x*64 + w*16;
  const int c0 = blockIdx.y*64;
  const int b = c0 >> 10, s0 = c0 & 1023;
  const f4 fz = {0.f,0.f,0.f,0.f};
  f4 acc[4] = {fz,fz,fz,fz};
  const unsigned short* arow = wv + (size_t)(n0 + p)*1024;
  for (int k0=0; k0<1024; k0+=32){
    bfx8 a = *(const bfx8*)(arow + k0 + 8*g);
#pragma unroll
    for (int f=0; f<4; ++f){
      bfx8 bb = *(const bfx8*)(xbf + ((size_t)((s0 + 16*f + p)*4 + b))*1024 + k0 + 8*g);
      acc[f] = mfma32(a, bb, acc[f]);
    }
  }
#pragma unroll
  for (int f=0; f<4; ++f){
#pragma unroll
    for (int r=0; r<4; ++r){
      int n = n0 + 4*g + r; int h = n >> 6, d = n & 63;
      int srow = s0 + 16*f + p;
      VT[((size_t)(b*16 + h)*64 + d)*1024 + srow] = f2bf(acc[f][r]);
    }
  }
}

// ---------------- Qr[bh][s][272] = Qscaled @ rel_k^T (bf16) ----------------
__global__ __launch_bounds__(256) void k_qr(
    const unsigned short* __restrict__ Qb, const unsigned short* __restrict__ relk,
    unsigned short* __restrict__ Qr)
{
  const int bh = blockIdx.x;
  const int w = threadIdx.x >> 6, lane = threadIdx.x & 63;
  const int p = lane & 15, g = lane >> 4;
  const int s0 = blockIdx.y*64 + w*16;
  const f4 fz = {0.f,0.f,0.f,0.f};
  bfx8 a0 = *(const bfx8*)(Qb + ((size_t)bh*1024 + s0 + p)*64 + 8*g);
  bfx8 a1 = *(const bfx8*)(Qb + ((size_t)bh*1024 + s0 + p)*64 + 32 + 8*g);
  for (int r0=0; r0<272; r0+=16){
    f4 acc = fz;
    bfx8 b0 = *(const bfx8*)(relk + (size_t)(r0 + p)*64 + 8*g);
    bfx8 b1 = *(const bfx8*)(relk + (size_t)(r0 + p)*64 + 32 + 8*g);
    acc = mfma32(a0, b0, acc);
    acc = mfma32(a1, b1, acc);
#pragma unroll
    for (int r=0; r<4; ++r)
      Qr[((size_t)bh*1024 + s0 + 4*g + r)*272 + r0 + p] = f2bf(acc[r]);
  }
}

// ---------------- fused attention ----------------
// block: (b, s-tile of 16). 4 waves = 4 head-groups of 4 heads. t-loop over 64 tiles of 16.
// scores computed TRANSPOSED: S^T = K @ Q^T, so attn^T D-frag feeds PV B-operand in-lane.
__global__ __launch_bounds__(256) void k_attn(
    const unsigned short* __restrict__ Qb, const unsigned short* __restrict__ Kb,
    const unsigned short* __restrict__ VT, const unsigned short* __restrict__ Qr,
    unsigned short* __restrict__ attnS, float* __restrict__ tails,
    unsigned short* __restrict__ out1)
{
  __shared__ __align__(16) float red[2][2][4][256];
  __shared__ __align__(16) float tbuf[16][16][68];
  const int bid = blockIdx.x;
  const int b = bid >> 6;
  const int s0 = (bid & 63) << 4;
  const int w = threadIdx.x >> 6;
  const int lane = threadIdx.x & 63;
  const int p = lane & 15, g = lane >> 4;
  const int s = s0 + p;
  const int h0 = w * 4;
  const f4 fz = {0.f,0.f,0.f,0.f};

  bfx8 qf[4][2];
#pragma unroll
  for (int hh=0; hh<4; ++hh){
    size_t base = ((size_t)(b*16 + h0 + hh) * 1024 + s) * 64;
#pragma unroll
    for (int kf=0; kf<2; ++kf)
      qf[hh][kf] = *(const bfx8*)(Qb + base + kf*32 + 8*g);
  }

  f4 o[4][4];
#pragma unroll
  for (int hh=0; hh<4; ++hh)
#pragma unroll
    for (int df=0; df<4; ++df) o[hh][df] = fz;

  float tl0[4] = {0.f,0.f,0.f,0.f};
  float tl1[4] = {0.f,0.f,0.f,0.f};

  bfx8 kc[4][2]; bfx4 vc[4][4]; unsigned short qc[4][4];
  bfx8 kn[4][2]; bfx4 vn[4][4]; unsigned short qn[4][4];

#pragma unroll
  for (int hh=0; hh<4; ++hh){
    size_t bh = (size_t)(b*16 + h0 + hh);
#pragma unroll
    for (int kf=0; kf<2; ++kf)
      kc[hh][kf] = *(const bfx8*)(Kb + (bh*1024 + p)*64 + kf*32 + 8*g);
#pragma unroll
    for (int df=0; df<4; ++df)
      vc[hh][df] = *(const bfx4*)(VT + (bh*64 + df*16 + p)*1024 + 4*g);
#pragma unroll
    for (int r=0; r<4; ++r){
      int t = 4*g + r;
      int u = s - t + 128; u = u < 0 ? 0 : (u > 256 ? 256 : u);
      qc[hh][r] = Qr[(bh*1024 + s)*272 + u];
    }
  }

  for (int it=0; it<64; ++it){
    const int t0 = it << 4;
    const int buf = it & 1;

    f4 sc[4];
#pragma unroll
    for (int hh=0; hh<4; ++hh){
      f4 t = mfma32(kc[hh][0], qf[hh][0], fz);
      sc[hh] = mfma32(kc[hh][1], qf[hh][1], t);
    }

    if (it < 63){
      const int t1 = t0 + 16;
#pragma unroll
      for (int hh=0; hh<4; ++hh){
        size_t bh = (size_t)(b*16 + h0 + hh);
#pragma unroll
        for (int kf=0; kf<2; ++kf)
          kn[hh][kf] = *(const bfx8*)(Kb + (bh*1024 + t1 + p)*64 + kf*32 + 8*g);
#pragma unroll
        for (int df=0; df<4; ++df)
          vn[hh][df] = *(const bfx4*)(VT + (bh*64 + df*16 + p)*1024 + t1 + 4*g);
#pragma unroll
        for (int r=0; r<4; ++r){
          int t = t1 + 4*g + r;
          int u = s - t + 128; u = u < 0 ? 0 : (u > 256 ? 256 : u);
          qn[hh][r] = Qr[(bh*1024 + s)*272 + u];
        }
      }
    }

#pragma unroll
    for (int hh=0; hh<4; ++hh)
#pragma unroll
      for (int r=0; r<4; ++r) sc[hh][r] += bf2f(qc[hh][r]);

    // softmax over the 16 heads (4 local frags x 4 waves), elementwise per (s,t)
    f4 pm = sc[0];
#pragma unroll
    for (int hh=1; hh<4; ++hh)
#pragma unroll
      for (int r=0; r<4; ++r) pm[r] = fmaxf(pm[r], sc[hh][r]);
    *(f4*)&red[0][buf][w][lane*4] = pm;
    __syncthreads();
    f4 m = *(const f4*)&red[0][buf][0][lane*4];
#pragma unroll
    for (int ww=1; ww<4; ++ww){
      f4 t = *(const f4*)&red[0][buf][ww][lane*4];
#pragma unroll
      for (int r=0; r<4; ++r) m[r] = fmaxf(m[r], t[r]);
    }
    f4 e[4]; f4 ps = fz;
#pragma unroll
    for (int hh=0; hh<4; ++hh)
#pragma unroll
      for (int r=0; r<4; ++r){ float v = __expf(sc[hh][r] - m[r]); e[hh][r] = v; ps[r] += v; }
    *(f4*)&red[1][buf][w][lane*4] = ps;
    __syncthreads();
    f4 S = *(const f4*)&red[1][buf][0][lane*4];
#pragma unroll
    for (int ww=1; ww<4; ++ww){
      f4 t = *(const f4*)&red[1][buf][ww][lane*4];
#pragma unroll
      for (int r=0; r<4; ++r) S[r] += t[r];
    }
    f4 inv;
#pragma unroll
    for (int r=0; r<4; ++r) inv[r] = 1.0f / S[r];

#pragma unroll
    for (int hh=0; hh<4; ++hh){
      size_t bh = (size_t)(b*16 + h0 + hh);
      f4 at;
#pragma unroll
      for (int r=0; r<4; ++r) at[r] = e[hh][r] * inv[r];
#pragma unroll
      for (int r=0; r<4; ++r){
        int t = t0 + 4*g + r;
        int u = s - t + 128;
        float a = at[r];
        if (u <= 0) tl0[hh] += a;
        else if (u >= 256) tl1[hh] += a;
        else attnS[(bh*1024 + s)*288 + u] = f2bf(a);
      }
      bfx4 pk;
#pragma unroll
      for (int r=0; r<4; ++r) pk[r] = (short)f2bf(at[r]);
#pragma unroll
      for (int df=0; df<4; ++df)
        o[hh][df] = mfma16(vc[hh][df], pk, o[hh][df]);
    }

    if (it < 63){
#pragma unroll
      for (int hh=0; hh<4; ++hh){
#pragma unroll
        for (int kf=0; kf<2; ++kf) kc[hh][kf] = kn[hh][kf];
#pragma unroll
        for (int df=0; df<4; ++df) vc[hh][df] = vn[hh][df];
#pragma unroll
        for (int r=0; r<4; ++r) qc[hh][r] = qn[hh][r];
      }
    }
  }

  // tail sums (r=0 / r=256 buckets), reduce over the 4 lane-groups
#pragma unroll
  for (int hh=0; hh<4; ++hh){
    float v0 = tl0[hh];
    v0 += __shfl_xor(v0, 16, 64);
    v0 += __shfl_xor(v0, 32, 64);
    float v1 = tl1[hh];
    v1 += __shfl_xor(v1, 16, 64);
    v1 += __shfl_xor(v1, 32, 64);
    if (g == 0){
      size_t bh = (size_t)(b*16 + h0 + hh);
      tails[(bh*1024 + s)*2 + 0] = v0;
      tails[(bh*1024 + s)*2 + 1] = v1;
    }
  }

  // write out1[b][s][h*64+d] (transpose O^T frags via LDS, coalesced bf16 stores)
#pragma unroll
  for (int hh=0; hh<4; ++hh){
    float (*tb)[68] = tbuf[w*4 + hh];
#pragma unroll
    for (int df=0; df<4; ++df)
      *(f4*)&tb[p][df*16 + 4*g] = o[hh][df];
    __syncthreads();
    const int srow = lane >> 2, quad = lane & 3;
    f4 r0 = *(const f4*)&tb[srow][quad*16 + 0];
    f4 r1 = *(const f4*)&tb[srow][quad*16 + 4];
    f4 r2 = *(const f4*)&tb[srow][quad*16 + 8];
    f4 r3 = *(const f4*)&tb[srow][quad*16 + 12];
    bfx8 pa, pb;
#pragma unroll
    for (int j=0; j<4; ++j){
      pa[j]   = (short)f2bf(r0[j]);
      pa[j+4] = (short)f2bf(r1[j]);
      pb[j]   = (short)f2bf(r2[j]);
      pb[j+4] = (short)f2bf(r3[j]);
    }
    size_t addr = ((size_t)b*1024 + s0 + srow)*1024 + (h0+hh)*64 + quad*16;
    *(bfx8*)(out1 + addr) = pa;
    *(bfx8*)(out1 + addr + 8) = pb;
    __syncthreads();
  }
}

// ---------------- out2^T = rel_v^T @ attnS^T (+ tails), RMW into out1 ----------------
__global__ __launch_bounds__(256) void k_outrel(
    const unsigned short* __restrict__ attnS, const unsigned short* __restrict__ relvT,
    const float* __restrict__ tails, const float* __restrict__ relv,
    unsigned short* __restrict__ out1)
{
  __shared__ __align__(16) float tbuf[4][16][68];
  const int bh = blockIdx.x;
  const int w = threadIdx.x >> 6, lane = threadIdx.x & 63;
  const int p = lane & 15, g = lane >> 4;
  const int s0 = blockIdx.y*64 + w*16;
  const f4 fz = {0.f,0.f,0.f,0.f};
  f4 acc[4] = {fz,fz,fz,fz};
  const size_t arow = ((size_t)bh*1024 + s0 + p)*288;
#pragma unroll
  for (int kk=0; kk<288; kk+=32){
    bfx8 bb = *(const bfx8*)(attnS + arow + kk + 8*g);
#pragma unroll
    for (int df=0; df<4; ++df){
      bfx8 a = *(const bfx8*)(relvT + (size_t)(df*16 + p)*288 + kk + 8*g);
      acc[df] = mfma32(a, bb, acc[df]);
    }
  }
  float tv0 = tails[((size_t)bh*1024 + s0 + p)*2 + 0];
  float tv1 = tails[((size_t)bh*1024 + s0 + p)*2 + 1];
#pragma unroll
  for (int df=0; df<4; ++df)
#pragma unroll
    for (int r=0; r<4; ++r){
      int d = df*16 + 4*g + r;
      acc[df][r] += tv0 * relv[d] + tv1 * relv[256*64 + d];
    }
  float (*tb)[68] = tbuf[w];
#pragma unroll
  for (int df=0; df<4; ++df)
    *(f4*)&tb[p][df*16 + 4*g] = acc[df];
  __syncthreads();
  const int srow = lane >> 2, quad = lane & 3;
  f4 r0 = *(const f4*)&tb[srow][quad*16 + 0];
  f4 r1 = *(const f4*)&tb[srow][quad*16 + 4];
  f4 r2 = *(const f4*)&tb[srow][quad*16 + 8];
  f4 r3 = *(const f4*)&tb[srow][quad*16 + 12];
  size_t addr = ((size_t)(bh>>4)*1024 + s0 + srow)*1024 + (bh&15)*64 + quad*16;
  bfx8 o0 = *(bfx8*)(out1 + addr);
  bfx8 o1 = *(bfx8*)(out1 + addr + 8);
  bfx8 n0v, n1v;
#pragma unroll
  for (int j=0; j<4; ++j){
    n0v[j]   = (short)f2bf(bf2f((unsigned short)o0[j])   + r0[j]);
    n0v[j+4] = (short)f2bf(bf2f((unsigned short)o0[j+4]) + r1[j]);
    n1v[j]   = (short)f2bf(bf2f((unsigned short)o1[j])   + r2[j]);
    n1v[j+4] = (short)f2bf(bf2f((unsigned short)o1[j+4]) + r3[j]);
  }
  *(bfx8*)(out1 + addr) = n0v;
  *(bfx8*)(out1 + addr + 8) = n1v;
}

// ---------------- final projection: d_out[(s,b)][n] = out1 @ w_o^T + b_o ----------------
__global__ __launch_bounds__(256) void k_wo(
    const unsigned short* __restrict__ out1, const unsigned short* __restrict__ wo,
    const float* __restrict__ bo, float* __restrict__ dout)
{
  const int bm = blockIdx.x;
  const int b = bm >> 4;
  const int w = threadIdx.x >> 6, lane = threadIdx.x & 63;
  const int p = lane & 15, g = lane >> 4;
  const int s0 = (bm & 15)*64 + w*16;
  const int n0 = blockIdx.y*64;
  const f4 fz = {0.f,0.f,0.f,0.f};
  f4 acc[4] = {fz,fz,fz,fz};
  const unsigned short* arow = out1 + ((size_t)b*1024 + s0 + p)*1024;
  for (int k0=0; k0<1024; k0+=32){
    bfx8 a = *(const bfx8*)(arow + k0 + 8*g);
#pragma unroll
    for (int f=0; f<4; ++f){
      bfx8 bb = *(const bfx8*)(wo + (size_t)(n0 + 16*f + p)*1024 + k0 + 8*g);
      acc[f] = mfma32(a, bb, acc[f]);
    }
  }
#pragma unroll
  for (int f=0; f<4; ++f){
    int col = n0 + 16*f + p;
    float bias = bo[col];
#pragma unroll
    for (int r=0; r<4; ++r){
      int srow = s0 + 4*g + r;
      dout[((size_t)srow*4 + b)*1024 + col] = acc[f][r] + bias;
    }
  }
}

extern "C" void kernel_launch(void* const* d_in, const int* in_sizes, int n_in,
                              void* d_out, int out_size, void* d_ws, size_t ws_size,
                              hipStream_t stream){
  const float* x   = (const float*)d_in[0];
  const float* wq  = (const float*)d_in[1];
  const float* wk  = (const float*)d_in[2];
  const float* wv  = (const float*)d_in[3];
  const float* wo  = (const float*)d_in[4];
  const float* bo  = (const float*)d_in[5];
  const float* rlk = (const float*)d_in[6];
  const float* rlv = (const float*)d_in[7];
  char* ws = (char*)d_ws;

  unsigned short* x_bf    = (unsigned short*)(ws + 0);
  unsigned short* wq_bf   = (unsigned short*)(ws + 8388608);
  unsigned short* wk_bf   = (unsigned short*)(ws + 10485760);
  unsigned short* wv_bf   = (unsigned short*)(ws + 12582912);
  unsigned short* wo_bf   = (unsigned short*)(ws + 14680064);
  unsigned short* relk_bf = (unsigned short*)(ws + 16777216);
  unsigned short* relvT_bf= (unsigned short*)(ws + 16812032);
  unsigned short* Qb      = (unsigned short*)(ws + 16848896);
  unsigned short* Kb      = (unsigned short*)(ws + 25237504);
  unsigned short* VT      = (unsigned short*)(ws + 33626112);
  unsigned short* Qr      = (unsigned short*)(ws + 42014720);
  unsigned short* attnS   = (unsigned short*)(ws + 77666304);
  float*          tails   = (float*)        (ws + 115415040);
  unsigned short* out1    = (unsigned short*)(ws + 115939328);
  // total ws use: 124,327,936 bytes

  k_cast<<<4096, 256, 0, stream>>>(x,  x_bf,  1048576);
  k_cast<<<1024, 256, 0, stream>>>(wq, wq_bf, 262144);
  k_cast<<<1024, 256, 0, stream>>>(wk, wk_bf, 262144);
  k_cast<<<1024, 256, 0, stream>>>(wv, wv_bf, 262144);
  k_cast<<<1024, 256, 0, stream>>>(wo, wo_bf, 262144);
  k_relprep<<<72, 256, 0, stream>>>(rlk, rlv, relk_bf, relvT_bf);

  k_qk<<<dim3(64,32), 256, 0, stream>>>(x_bf, wq_bf, wk_bf, Qb, Kb);
  k_v <<<dim3(16,64), 256, 0, stream>>>(x_bf, wv_bf, VT);
  k_qr<<<dim3(64,16), 256, 0, stream>>>(Qb, relk_bf, Qr);

  (void)hipMemsetAsync(attnS, 0, (size_t)37748736, stream);
  k_attn<<<256, 256, 0, stream>>>(Qb, Kb, VT, Qr, attnS, tails, out1);
  k_outrel<<<dim3(64,16), 256, 0, stream>>>(attnS, relvT_bf, tails, rlv, out1);
  k_wo<<<dim3(64,16), 256, 0, stream>>>(out1, wo_bf, bo, (float*)d_out);
}